// Round 1
// baseline (673.321 us; speedup 1.0000x reference)
//
#include <hip/hip_runtime.h>
#include <hip/hip_bf16.h>

// FlashMultiHeadAttention: x -> Q,K,V proj -> causal GQA flash attn -> out proj
// B=2 N=2048 E=2048 HQ=32 HKV=8 D=64 G=4. All compute in bf16 MFMA, fp32 accum.

#define B_   2
#define N_   2048
#define E_   2048
#define HQ_  32
#define HKV_ 8
#define D_   64
#define G_   4
#define BN_  (B_*N_)   // 4096 total rows

typedef __attribute__((ext_vector_type(8))) short bf16x8;
typedef __attribute__((ext_vector_type(4))) float f32x4;

#define MFMA16(a,b,c) __builtin_amdgcn_mfma_f32_16x16x32_bf16(a,b,c,0,0,0)

__device__ inline unsigned short f2bf(float f) {
  unsigned u = __builtin_bit_cast(unsigned, f);
  u += 0x7FFFu + ((u >> 16) & 1u);   // RNE
  return (unsigned short)(u >> 16);
}

__device__ inline void gload_lds16(const void* g, void* l) {
  __builtin_amdgcn_global_load_lds(
      (const __attribute__((address_space(1))) void*)g,
      (__attribute__((address_space(3))) void*)l, 16, 0, 0);
}

// ---------------- cast fp32 -> bf16 (vectorized) ----------------
__global__ void cast_kernel(const float* __restrict__ in,
                            unsigned short* __restrict__ out, int n4) {
  int i = blockIdx.x * blockDim.x + threadIdx.x;
  int stride = gridDim.x * blockDim.x;
  for (; i < n4; i += stride) {
    float4 f = reinterpret_cast<const float4*>(in)[i];
    ushort4 u;
    u.x = f2bf(f.x); u.y = f2bf(f.y); u.z = f2bf(f.z); u.w = f2bf(f.w);
    reinterpret_cast<ushort4*>(out)[i] = u;
  }
}

// ---------------- GEMM: C[M][Nout] = A[M][K] @ W[Nout][K]^T + bias ----------------
// A,W bf16 row-major (K contiguous). OUT_MODE: 0=bf16 C[M][Nout], 1=fp32 C[M][Nout],
// 2=bf16 transposed Ct[Nout][M] (used for V so attention reads V^T contiguously).
// 128x128 tile, BK=32, 4 waves each computing 64x64. m97-style global_load_lds staging.
template<int OUT_MODE>
__global__ __launch_bounds__(256) void gemm_bt(
    const unsigned short* __restrict__ A, const unsigned short* __restrict__ W,
    const float* __restrict__ bias, void* __restrict__ Cv,
    int M, int Nout, int K)
{
  __shared__ unsigned short As[128*32];
  __shared__ unsigned short Bs[128*32];
  const int tid  = threadIdx.x;
  const int w    = tid >> 6;
  const int lane = tid & 63;
  const int nbx  = Nout >> 7;
  const int bm   = blockIdx.x / nbx;
  const int bn   = blockIdx.x - bm * nbx;
  const int m0   = bm << 7, n0 = bn << 7;
  const int wr   = (w >> 1) << 6;   // wave row offset 0/64
  const int wc   = (w & 1) << 6;    // wave col offset 0/64
  const int cl   = lane & 15;
  const int kgrp = lane >> 4;       // 0..3
  const int rl   = kgrp << 2;

  // staging geometry: wave w stages tile rows [w*32, w*32+32), 2 issues of 1KB each
  const int srow = w << 5;
  const int r0   = lane >> 2;          // 0..15
  const int c0   = (lane & 3) << 3;    // element col 0,8,16,24
  const unsigned short* ga0 = A + (size_t)(m0 + srow + r0) * K + c0;
  const unsigned short* ga1 = A + (size_t)(m0 + srow + 16 + r0) * K + c0;
  const unsigned short* gb0 = W + (size_t)(n0 + srow + r0) * K + c0;
  const unsigned short* gb1 = W + (size_t)(n0 + srow + 16 + r0) * K + c0;
  unsigned short* la0 = As + (w << 10);
  unsigned short* la1 = As + (w << 10) + 512;
  unsigned short* lb0 = Bs + (w << 10);
  unsigned short* lb1 = Bs + (w << 10) + 512;

  f32x4 acc[4][4] = {};

  const int nk = K >> 5;
  for (int kt = 0; kt < nk; ++kt) {
    const int ko = kt << 5;
    gload_lds16(ga0 + ko, la0);
    gload_lds16(ga1 + ko, la1);
    gload_lds16(gb0 + ko, lb0);
    gload_lds16(gb1 + ko, lb1);
    __syncthreads();   // drains vmcnt -> tiles ready
    bf16x8 af[4], bfr[4];
    #pragma unroll
    for (int i = 0; i < 4; ++i)
      af[i] = *reinterpret_cast<const bf16x8*>(&As[(wr + i*16 + cl)*32 + (kgrp << 3)]);
    #pragma unroll
    for (int j = 0; j < 4; ++j)
      bfr[j] = *reinterpret_cast<const bf16x8*>(&Bs[(wc + j*16 + cl)*32 + (kgrp << 3)]);
    #pragma unroll
    for (int i = 0; i < 4; ++i)
      #pragma unroll
      for (int j = 0; j < 4; ++j)
        acc[i][j] = MFMA16(af[i], bfr[j], acc[i][j]);
    __syncthreads();   // protect LDS before next stage
  }

  // epilogue. C layout: col = lane&15, row = (lane>>4)*4 + r  [m89/m91]
  if (OUT_MODE == 0) {
    unsigned short* C = (unsigned short*)Cv;
    #pragma unroll
    for (int j = 0; j < 4; ++j) {
      const int col = n0 + wc + j*16 + cl;
      const float bj = bias[col];
      #pragma unroll
      for (int i = 0; i < 4; ++i) {
        const int row = m0 + wr + i*16 + rl;
        #pragma unroll
        for (int r = 0; r < 4; ++r)
          C[(size_t)(row + r) * Nout + col] = f2bf(acc[i][j][r] + bj);
      }
    }
  } else if (OUT_MODE == 1) {
    float* C = (float*)Cv;
    #pragma unroll
    for (int j = 0; j < 4; ++j) {
      const int col = n0 + wc + j*16 + cl;
      const float bj = bias[col];
      #pragma unroll
      for (int i = 0; i < 4; ++i) {
        const int row = m0 + wr + i*16 + rl;
        #pragma unroll
        for (int r = 0; r < 4; ++r)
          C[(size_t)(row + r) * Nout + col] = acc[i][j][r] + bj;
      }
    }
  } else {
    // transposed store: Ct[col][row], ld = M; 4 consecutive rows pack into ushort4
    unsigned short* C = (unsigned short*)Cv;
    #pragma unroll
    for (int j = 0; j < 4; ++j) {
      const int col = n0 + wc + j*16 + cl;
      const float bj = bias[col];
      #pragma unroll
      for (int i = 0; i < 4; ++i) {
        const int rowb = m0 + wr + i*16 + rl;
        ushort4 u;
        u.x = f2bf(acc[i][j][0] + bj);
        u.y = f2bf(acc[i][j][1] + bj);
        u.z = f2bf(acc[i][j][2] + bj);
        u.w = f2bf(acc[i][j][3] + bj);
        *reinterpret_cast<ushort4*>(&C[(size_t)col * M + rowb]) = u;
      }
    }
  }
}

// ---------------- causal GQA flash attention ----------------
// grid.x = N/64 (q blocks), grid.y = B*HQ. 4 waves/block, wave owns 16 q rows.
// Q[4096][2048] bf16, K[4096][512] bf16, Vt[512][4096] bf16 (transposed V), O[4096][2048] bf16.
__global__ __launch_bounds__(256) void attn_kernel(
    const unsigned short* __restrict__ Q, const unsigned short* __restrict__ K,
    const unsigned short* __restrict__ Vt, unsigned short* __restrict__ O)
{
  __shared__ unsigned short Ps[4*16*32];   // per-wave P round-trip buffer
  const int tid  = threadIdx.x;
  const int w    = tid >> 6;
  const int lane = tid & 63;
  const int head = blockIdx.y;       // b*HQ + hq
  const int b    = head >> 5;
  const int hq   = head & 31;
  const int h    = hq >> 2;          // kv head
  const int q0   = blockIdx.x * 64 + w * 16;
  const int cl   = lane & 15;
  const int kgrp = lane >> 4;
  const int rl   = kgrp << 2;

  const float K2 = 0.125f * 1.44269504088896340736f;  // SCALE * log2(e)

  const size_t qoff = (size_t)(b*N_ + q0 + cl) * E_ + hq*D_ + (kgrp << 3);
  const bf16x8 qf0 = *reinterpret_cast<const bf16x8*>(Q + qoff);
  const bf16x8 qf1 = *reinterpret_cast<const bf16x8*>(Q + qoff + 32);

  f32x4 o[4] = {};
  float m[4], l[4];
  #pragma unroll
  for (int r = 0; r < 4; ++r) { m[r] = -1e30f; l[r] = 0.f; }

  unsigned short* pw = Ps + w*512;
  const unsigned short* Kb = K + (size_t)(b*N_) * (HKV_*D_) + h*D_ + (kgrp << 3);
  const unsigned short* Vb = Vt + (size_t)(h*D_ + cl) * BN_ + b*N_;

  const int ntile = (q0 + 47) >> 5;
  for (int t = 0; t < ntile; ++t) {
    const int kv0 = t << 5;
    // ---- S = Q K^T (two 16-col blocks) ----
    f32x4 s[2];
    #pragma unroll
    for (int c = 0; c < 2; ++c) {
      const unsigned short* kp = Kb + (size_t)(kv0 + c*16 + cl) * (HKV_*D_);
      bf16x8 bk0 = *reinterpret_cast<const bf16x8*>(kp);
      bf16x8 bk1 = *reinterpret_cast<const bf16x8*>(kp + 32);
      f32x4 z = {};
      z = MFMA16(qf0, bk0, z);
      z = MFMA16(qf1, bk1, z);
      s[c] = z;
    }
    // ---- causal mask (only diagonal tiles) ----
    if (kv0 + 31 > q0) {
      #pragma unroll
      for (int c = 0; c < 2; ++c)
        #pragma unroll
        for (int r = 0; r < 4; ++r)
          if (kv0 + c*16 + cl > q0 + rl + r) s[c][r] = -1e30f;
    }
    // ---- online softmax ----
    float tm[4];
    #pragma unroll
    for (int r = 0; r < 4; ++r) tm[r] = fmaxf(s[0][r], s[1][r]);
    #pragma unroll
    for (int off = 1; off < 16; off <<= 1)
      #pragma unroll
      for (int r = 0; r < 4; ++r)
        tm[r] = fmaxf(tm[r], __shfl_xor(tm[r], off, 64));
    float alpha[4], ps[2][4], rsum[4];
    #pragma unroll
    for (int r = 0; r < 4; ++r) {
      float mn = fmaxf(m[r], tm[r]);
      alpha[r] = __builtin_amdgcn_exp2f(K2 * (m[r] - mn));
      m[r] = mn;
      rsum[r] = 0.f;
    }
    #pragma unroll
    for (int c = 0; c < 2; ++c)
      #pragma unroll
      for (int r = 0; r < 4; ++r) {
        float p = __builtin_amdgcn_exp2f(K2 * (s[c][r] - m[r]));
        ps[c][r] = p;
        rsum[r] += p;
      }
    #pragma unroll
    for (int off = 1; off < 16; off <<= 1)
      #pragma unroll
      for (int r = 0; r < 4; ++r)
        rsum[r] += __shfl_xor(rsum[r], off, 64);
    #pragma unroll
    for (int r = 0; r < 4; ++r) l[r] = l[r] * alpha[r] + rsum[r];
    #pragma unroll
    for (int db = 0; db < 4; ++db)
      #pragma unroll
      for (int r = 0; r < 4; ++r) o[db][r] *= alpha[r];
    // ---- P (C-layout) -> LDS -> A-layout ----
    #pragma unroll
    for (int c = 0; c < 2; ++c)
      #pragma unroll
      for (int r = 0; r < 4; ++r)
        pw[(rl + r)*32 + c*16 + cl] = f2bf(ps[c][r]);
    bf16x8 pa = *reinterpret_cast<const bf16x8*>(&pw[cl*32 + (kgrp << 3)]);
    // ---- O += P V  (B operand from Vt, contiguous) ----
    #pragma unroll
    for (int db = 0; db < 4; ++db) {
      const unsigned short* vp = Vb + (size_t)(db*16) * BN_ + kv0 + (kgrp << 3);
      bf16x8 bv = *reinterpret_cast<const bf16x8*>(vp);
      o[db] = MFMA16(pa, bv, o[db]);
    }
  }
  // ---- epilogue: O[row][hq*64 + d] = o/l ----
  #pragma unroll
  for (int r = 0; r < 4; ++r) {
    const float inv = 1.0f / l[r];
    const size_t orow = (size_t)(b*N_ + q0 + rl + r) * E_ + hq*D_;
    #pragma unroll
    for (int db = 0; db < 4; ++db)
      O[orow + db*16 + cl] = f2bf(o[db][r] * inv);
  }
}

extern "C" void kernel_launch(void* const* d_in, const int* in_sizes, int n_in,
                              void* d_out, int out_size, void* d_ws, size_t ws_size,
                              hipStream_t stream) {
  const float* x  = (const float*)d_in[0];
  const float* Wq = (const float*)d_in[1];
  const float* bq = (const float*)d_in[2];
  const float* Wk = (const float*)d_in[3];
  const float* bk = (const float*)d_in[4];
  const float* Wv = (const float*)d_in[5];
  const float* bv = (const float*)d_in[6];
  const float* Wo = (const float*)d_in[7];
  const float* bo = (const float*)d_in[8];
  float* out = (float*)d_out;

  // workspace carve (bf16 elements); total ~80 MB
  unsigned short* ws  = (unsigned short*)d_ws;
  unsigned short* xb  = ws;              // 4096x2048
  unsigned short* Wqb = xb  + 8388608;   // 2048x2048
  unsigned short* Wkb = Wqb + 4194304;   // 512x2048
  unsigned short* Wvb = Wkb + 1048576;   // 512x2048
  unsigned short* Wob = Wvb + 1048576;   // 2048x2048
  unsigned short* Qb  = Wob + 4194304;   // 4096x2048
  unsigned short* Kb  = Qb  + 8388608;   // 4096x512
  unsigned short* Vtb = Kb  + 2097152;   // 512x4096 (V transposed)
  unsigned short* Ob  = Vtb + 2097152;   // 4096x2048

  auto cast = [&](const float* in, unsigned short* o, int n) {
    int n4 = n >> 2;
    int blocks = (n4 + 255) >> 8; if (blocks > 8192) blocks = 8192;
    cast_kernel<<<dim3(blocks), dim3(256), 0, stream>>>(in, o, n4);
  };
  cast(x,  xb,  BN_*E_);
  cast(Wq, Wqb, E_*E_);
  cast(Wk, Wkb, HKV_*D_*E_);
  cast(Wv, Wvb, HKV_*D_*E_);
  cast(Wo, Wob, E_*E_);

  // projections
  gemm_bt<0><<<dim3(32*16), dim3(256), 0, stream>>>(xb, Wqb, bq, Qb,  BN_, E_,       E_);
  gemm_bt<0><<<dim3(32*4),  dim3(256), 0, stream>>>(xb, Wkb, bk, Kb,  BN_, HKV_*D_,  E_);
  gemm_bt<2><<<dim3(32*4),  dim3(256), 0, stream>>>(xb, Wvb, bv, Vtb, BN_, HKV_*D_,  E_);

  // causal GQA flash attention
  attn_kernel<<<dim3(N_/64, B_*HQ_), dim3(256), 0, stream>>>(Qb, Kb, Vtb, Ob);

  // output projection (fp32 out)
  gemm_bt<1><<<dim3(32*16), dim3(256), 0, stream>>>(Ob, Wob, bo, out, BN_, E_, E_);
}

// Round 2
// 358.585 us; speedup vs baseline: 1.8777x; 1.8777x over previous
//
#include <hip/hip_runtime.h>
#include <hip/hip_bf16.h>

// FlashMultiHeadAttention: x -> Q,K,V proj -> causal GQA flash attn -> out proj
// B=2 N=2048 E=2048 HQ=32 HKV=8 D=64 G=4. All compute in bf16 MFMA, fp32 accum.

#define B_   2
#define N_   2048
#define E_   2048
#define HQ_  32
#define HKV_ 8
#define D_   64
#define G_   4
#define BN_  (B_*N_)   // 4096 total rows

typedef __attribute__((ext_vector_type(8))) short bf16x8;
typedef __attribute__((ext_vector_type(4))) float f32x4;

#define MFMA16(a,b,c) __builtin_amdgcn_mfma_f32_16x16x32_bf16(a,b,c,0,0,0)

__device__ inline unsigned short f2bf(float f) {
  unsigned u = __builtin_bit_cast(unsigned, f);
  u += 0x7FFFu + ((u >> 16) & 1u);   // RNE
  return (unsigned short)(u >> 16);
}

__device__ inline void gload_lds16(const void* g, void* l) {
  __builtin_amdgcn_global_load_lds(
      (const __attribute__((address_space(1))) void*)g,
      (__attribute__((address_space(3))) void*)l, 16, 0, 0);
}

// ---------------- cast fp32 -> bf16 (vectorized) ----------------
__global__ void cast_kernel(const float* __restrict__ in,
                            unsigned short* __restrict__ out, int n4) {
  int i = blockIdx.x * blockDim.x + threadIdx.x;
  int stride = gridDim.x * blockDim.x;
  for (; i < n4; i += stride) {
    float4 f = reinterpret_cast<const float4*>(in)[i];
    ushort4 u;
    u.x = f2bf(f.x); u.y = f2bf(f.y); u.z = f2bf(f.z); u.w = f2bf(f.w);
    reinterpret_cast<ushort4*>(out)[i] = u;
  }
}

// ---------------- GEMM: C[M][Nout] = A[M][K] @ W[Nout][K]^T + bias ----------------
// A,W bf16 row-major (K contiguous). OUT_MODE: 0=bf16 C[M][Nout], 1=fp32 C[M][Nout],
// 2=bf16 transposed Ct[Nout][M] (used for V so attention reads V^T contiguously).
// 128x128 tile, BK=32, 4 waves each computing 64x64. m97-style global_load_lds staging.
template<int OUT_MODE>
__global__ __launch_bounds__(256) void gemm_bt(
    const unsigned short* __restrict__ A, const unsigned short* __restrict__ W,
    const float* __restrict__ bias, void* __restrict__ Cv,
    int M, int Nout, int K)
{
  __shared__ unsigned short As[128*32];
  __shared__ unsigned short Bs[128*32];
  const int tid  = threadIdx.x;
  const int w    = tid >> 6;
  const int lane = tid & 63;
  const int nbx  = Nout >> 7;
  const int bm   = blockIdx.x / nbx;
  const int bn   = blockIdx.x - bm * nbx;
  const int m0   = bm << 7, n0 = bn << 7;
  const int wr   = (w >> 1) << 6;   // wave row offset 0/64
  const int wc   = (w & 1) << 6;    // wave col offset 0/64
  const int cl   = lane & 15;
  const int kgrp = lane >> 4;       // 0..3
  const int rl   = kgrp << 2;

  // staging geometry: wave w stages tile rows [w*32, w*32+32), 2 issues of 1KB each
  const int srow = w << 5;
  const int r0   = lane >> 2;          // 0..15
  const int c0   = (lane & 3) << 3;    // element col 0,8,16,24
  const unsigned short* ga0 = A + (size_t)(m0 + srow + r0) * K + c0;
  const unsigned short* ga1 = A + (size_t)(m0 + srow + 16 + r0) * K + c0;
  const unsigned short* gb0 = W + (size_t)(n0 + srow + r0) * K + c0;
  const unsigned short* gb1 = W + (size_t)(n0 + srow + 16 + r0) * K + c0;
  unsigned short* la0 = As + (w << 10);
  unsigned short* la1 = As + (w << 10) + 512;
  unsigned short* lb0 = Bs + (w << 10);
  unsigned short* lb1 = Bs + (w << 10) + 512;

  f32x4 acc[4][4] = {};

  const int nk = K >> 5;
  for (int kt = 0; kt < nk; ++kt) {
    const int ko = kt << 5;
    gload_lds16(ga0 + ko, la0);
    gload_lds16(ga1 + ko, la1);
    gload_lds16(gb0 + ko, lb0);
    gload_lds16(gb1 + ko, lb1);
    __syncthreads();   // drains vmcnt -> tiles ready
    bf16x8 af[4], bfr[4];
    #pragma unroll
    for (int i = 0; i < 4; ++i)
      af[i] = *reinterpret_cast<const bf16x8*>(&As[(wr + i*16 + cl)*32 + (kgrp << 3)]);
    #pragma unroll
    for (int j = 0; j < 4; ++j)
      bfr[j] = *reinterpret_cast<const bf16x8*>(&Bs[(wc + j*16 + cl)*32 + (kgrp << 3)]);
    #pragma unroll
    for (int i = 0; i < 4; ++i)
      #pragma unroll
      for (int j = 0; j < 4; ++j)
        acc[i][j] = MFMA16(af[i], bfr[j], acc[i][j]);
    __syncthreads();   // protect LDS before next stage
  }

  // epilogue. C layout: col = lane&15, row = (lane>>4)*4 + r  [m89/m91]
  if (OUT_MODE == 0) {
    unsigned short* C = (unsigned short*)Cv;
    #pragma unroll
    for (int j = 0; j < 4; ++j) {
      const int col = n0 + wc + j*16 + cl;
      const float bj = bias[col];
      #pragma unroll
      for (int i = 0; i < 4; ++i) {
        const int row = m0 + wr + i*16 + rl;
        #pragma unroll
        for (int r = 0; r < 4; ++r)
          C[(size_t)(row + r) * Nout + col] = f2bf(acc[i][j][r] + bj);
      }
    }
  } else if (OUT_MODE == 1) {
    float* C = (float*)Cv;
    #pragma unroll
    for (int j = 0; j < 4; ++j) {
      const int col = n0 + wc + j*16 + cl;
      const float bj = bias[col];
      #pragma unroll
      for (int i = 0; i < 4; ++i) {
        const int row = m0 + wr + i*16 + rl;
        #pragma unroll
        for (int r = 0; r < 4; ++r)
          C[(size_t)(row + r) * Nout + col] = acc[i][j][r] + bj;
      }
    }
  } else {
    // transposed store: Ct[col][row], ld = M; 4 consecutive rows pack into ushort4
    unsigned short* C = (unsigned short*)Cv;
    #pragma unroll
    for (int j = 0; j < 4; ++j) {
      const int col = n0 + wc + j*16 + cl;
      const float bj = bias[col];
      #pragma unroll
      for (int i = 0; i < 4; ++i) {
        const int rowb = m0 + wr + i*16 + rl;
        ushort4 u;
        u.x = f2bf(acc[i][j][0] + bj);
        u.y = f2bf(acc[i][j][1] + bj);
        u.z = f2bf(acc[i][j][2] + bj);
        u.w = f2bf(acc[i][j][3] + bj);
        *reinterpret_cast<ushort4*>(&C[(size_t)col * M + rowb]) = u;
      }
    }
  }
}

// ---------------- causal GQA flash attention (v2) ----------------
// grid = (8, B*HQ), 4 waves/block. Wave slot j = blockIdx.x*4 + w (0..31) handles
// the BALANCED strip pair (j, 63-j): two 32-row q-strips whose causal work sums
// to a constant (~65 kv-tiles) -> uniform work per wave, no tail.
// Per strip: 2 q-blocks of 16 rows (i=0,1), KVBLK=32, K prefetched 1 tile ahead,
// P round-trip through XOR-swizzled LDS (conflict-free).
// Q[4096][2048] bf16, K[4096][512] bf16, Vt[512][4096] bf16, O[4096][2048] bf16.
__global__ __launch_bounds__(256, 2) void attn_kernel(
    const unsigned short* __restrict__ Q, const unsigned short* __restrict__ K,
    const unsigned short* __restrict__ Vt, unsigned short* __restrict__ O)
{
  __shared__ __align__(16) unsigned short Ps[4*32*32];   // 2KB per wave
  const int tid  = threadIdx.x;
  const int w    = tid >> 6;
  const int lane = tid & 63;
  const int head = blockIdx.y;       // b*HQ + hq
  const int b    = head >> 5;
  const int hq   = head & 31;
  const int h    = hq >> 2;          // kv head
  const int jslot= blockIdx.x * 4 + w;  // 0..31
  const int cl   = lane & 15;
  const int kgrp = lane >> 4;
  const int rl   = kgrp << 2;

  const float K2 = 0.125f * 1.44269504088896340736f;  // SCALE * log2(e)

  unsigned short* pw = Ps + w*1024;
  const unsigned short* Kb = K + (size_t)(b*N_) * (HKV_*D_) + h*D_ + (kgrp << 3);
  const unsigned short* Vb = Vt + (size_t)(h*D_ + cl) * BN_ + b*N_;

  for (int sp = 0; sp < 2; ++sp) {
    const int sidx = sp ? (63 - jslot) : jslot;   // strip index 0..63
    const int q0   = sidx << 5;                   // first q row of strip

    // Q fragments: 2 i-blocks x 2 k-chunks
    bf16x8 qf[2][2];
    #pragma unroll
    for (int i = 0; i < 2; ++i) {
      const size_t qoff = (size_t)(b*N_ + q0 + i*16 + cl) * E_ + hq*D_ + (kgrp << 3);
      qf[i][0] = *reinterpret_cast<const bf16x8*>(Q + qoff);
      qf[i][1] = *reinterpret_cast<const bf16x8*>(Q + qoff + 32);
    }

    f32x4 o[2][4] = {};
    float m[2][4], l[2][4];
    #pragma unroll
    for (int i = 0; i < 2; ++i)
      #pragma unroll
      for (int r = 0; r < 4; ++r) { m[i][r] = -1e30f; l[i][r] = 0.f; }

    const int ntile = sidx + 1;   // kv tiles 0..sidx (kv <= q0+31)

    // prefetch K tile 0
    bf16x8 kf[2][2];
    #pragma unroll
    for (int c = 0; c < 2; ++c) {
      const unsigned short* kp = Kb + (size_t)(c*16 + cl) * (HKV_*D_);
      kf[c][0] = *reinterpret_cast<const bf16x8*>(kp);
      kf[c][1] = *reinterpret_cast<const bf16x8*>(kp + 32);
    }

    for (int t = 0; t < ntile; ++t) {
      const int kv0 = t << 5;
      // ---- issue V loads for this tile (consumed at PV, latency hidden) ----
      bf16x8 vf[4];
      #pragma unroll
      for (int db = 0; db < 4; ++db)
        vf[db] = *reinterpret_cast<const bf16x8*>(
            Vb + (size_t)(db*16) * BN_ + kv0 + (kgrp << 3));
      // ---- S = Q K^T ----
      f32x4 s[2][2];
      #pragma unroll
      for (int i = 0; i < 2; ++i)
        #pragma unroll
        for (int c = 0; c < 2; ++c) {
          f32x4 z = {};
          z = MFMA16(qf[i][0], kf[c][0], z);
          z = MFMA16(qf[i][1], kf[c][1], z);
          s[i][c] = z;
        }
      // ---- prefetch K for next tile (hidden under softmax+PV) ----
      {
        const int tn = (t + 1 < ntile) ? (t + 1) : t;
        #pragma unroll
        for (int c = 0; c < 2; ++c) {
          const unsigned short* kp = Kb + (size_t)((tn << 5) + c*16 + cl) * (HKV_*D_);
          kf[c][0] = *reinterpret_cast<const bf16x8*>(kp);
          kf[c][1] = *reinterpret_cast<const bf16x8*>(kp + 32);
        }
      }
      // ---- causal mask (diagonal tile only) ----
      #pragma unroll
      for (int i = 0; i < 2; ++i) {
        if (kv0 + 31 > q0 + i*16) {
          #pragma unroll
          for (int c = 0; c < 2; ++c)
            #pragma unroll
            for (int r = 0; r < 4; ++r)
              if (kv0 + c*16 + cl > q0 + i*16 + rl + r) s[i][c][r] = -1e30f;
        }
      }
      // ---- online softmax (both i-blocks reduce in parallel) ----
      float tm[2][4];
      #pragma unroll
      for (int i = 0; i < 2; ++i)
        #pragma unroll
        for (int r = 0; r < 4; ++r) tm[i][r] = fmaxf(s[i][0][r], s[i][1][r]);
      #pragma unroll
      for (int off = 1; off < 16; off <<= 1)
        #pragma unroll
        for (int i = 0; i < 2; ++i)
          #pragma unroll
          for (int r = 0; r < 4; ++r)
            tm[i][r] = fmaxf(tm[i][r], __shfl_xor(tm[i][r], off, 64));
      float alpha[2][4], ps[2][2][4], rsum[2][4];
      #pragma unroll
      for (int i = 0; i < 2; ++i)
        #pragma unroll
        for (int r = 0; r < 4; ++r) {
          float mn = fmaxf(m[i][r], tm[i][r]);
          alpha[i][r] = __builtin_amdgcn_exp2f(K2 * (m[i][r] - mn));
          m[i][r] = mn;
          rsum[i][r] = 0.f;
        }
      #pragma unroll
      for (int i = 0; i < 2; ++i)
        #pragma unroll
        for (int c = 0; c < 2; ++c)
          #pragma unroll
          for (int r = 0; r < 4; ++r) {
            float p = __builtin_amdgcn_exp2f(K2 * (s[i][c][r] - m[i][r]));
            ps[i][c][r] = p;
            rsum[i][r] += p;
          }
      #pragma unroll
      for (int off = 1; off < 16; off <<= 1)
        #pragma unroll
        for (int i = 0; i < 2; ++i)
          #pragma unroll
          for (int r = 0; r < 4; ++r)
            rsum[i][r] += __shfl_xor(rsum[i][r], off, 64);
      #pragma unroll
      for (int i = 0; i < 2; ++i) {
        #pragma unroll
        for (int r = 0; r < 4; ++r) l[i][r] = l[i][r] * alpha[i][r] + rsum[i][r];
        #pragma unroll
        for (int db = 0; db < 4; ++db)
          #pragma unroll
          for (int r = 0; r < 4; ++r) o[i][db][r] *= alpha[i][r];
      }
      // ---- P (C-layout) -> swizzled LDS -> A-layout ----
      // write: row = i*16 + rl + r; col group (c*2 + cl>>3) XOR'd with kgrp (=row>>2 &3)
      #pragma unroll
      for (int i = 0; i < 2; ++i)
        #pragma unroll
        for (int c = 0; c < 2; ++c)
          #pragma unroll
          for (int r = 0; r < 4; ++r)
            pw[(i*16 + rl + r)*32 + ((((c << 1) + (cl >> 3)) ^ kgrp) << 3) + (cl & 7)]
                = f2bf(ps[i][c][r]);
      // ---- O += P V ----
      #pragma unroll
      for (int i = 0; i < 2; ++i) {
        const bf16x8 pa = *reinterpret_cast<const bf16x8*>(
            &pw[(i*16 + cl)*32 + ((kgrp ^ (cl >> 2)) << 3)]);
        #pragma unroll
        for (int db = 0; db < 4; ++db)
          o[i][db] = MFMA16(pa, vf[db], o[i][db]);
      }
    }

    // ---- epilogue: O[row][hq*64 + d] = o/l ----
    #pragma unroll
    for (int i = 0; i < 2; ++i)
      #pragma unroll
      for (int r = 0; r < 4; ++r) {
        const float inv = 1.0f / l[i][r];
        const size_t orow = (size_t)(b*N_ + q0 + i*16 + rl + r) * E_ + hq*D_;
        #pragma unroll
        for (int db = 0; db < 4; ++db)
          O[orow + db*16 + cl] = f2bf(o[i][db][r] * inv);
      }
  }
}

extern "C" void kernel_launch(void* const* d_in, const int* in_sizes, int n_in,
                              void* d_out, int out_size, void* d_ws, size_t ws_size,
                              hipStream_t stream) {
  const float* x  = (const float*)d_in[0];
  const float* Wq = (const float*)d_in[1];
  const float* bq = (const float*)d_in[2];
  const float* Wk = (const float*)d_in[3];
  const float* bk = (const float*)d_in[4];
  const float* Wv = (const float*)d_in[5];
  const float* bv = (const float*)d_in[6];
  const float* Wo = (const float*)d_in[7];
  const float* bo = (const float*)d_in[8];
  float* out = (float*)d_out;

  // workspace carve (bf16 elements); total ~80 MB
  unsigned short* ws  = (unsigned short*)d_ws;
  unsigned short* xb  = ws;              // 4096x2048
  unsigned short* Wqb = xb  + 8388608;   // 2048x2048
  unsigned short* Wkb = Wqb + 4194304;   // 512x2048
  unsigned short* Wvb = Wkb + 1048576;   // 512x2048
  unsigned short* Wob = Wvb + 1048576;   // 2048x2048
  unsigned short* Qb  = Wob + 4194304;   // 4096x2048
  unsigned short* Kb  = Qb  + 8388608;   // 4096x512
  unsigned short* Vtb = Kb  + 2097152;   // 512x4096 (V transposed)
  unsigned short* Ob  = Vtb + 2097152;   // 4096x2048

  auto cast = [&](const float* in, unsigned short* o, int n) {
    int n4 = n >> 2;
    int blocks = (n4 + 255) >> 8; if (blocks > 8192) blocks = 8192;
    cast_kernel<<<dim3(blocks), dim3(256), 0, stream>>>(in, o, n4);
  };
  cast(x,  xb,  BN_*E_);
  cast(Wq, Wqb, E_*E_);
  cast(Wk, Wkb, HKV_*D_*E_);
  cast(Wv, Wvb, HKV_*D_*E_);
  cast(Wo, Wob, E_*E_);

  // projections
  gemm_bt<0><<<dim3(32*16), dim3(256), 0, stream>>>(xb, Wqb, bq, Qb,  BN_, E_,       E_);
  gemm_bt<0><<<dim3(32*4),  dim3(256), 0, stream>>>(xb, Wkb, bk, Kb,  BN_, HKV_*D_,  E_);
  gemm_bt<2><<<dim3(32*4),  dim3(256), 0, stream>>>(xb, Wvb, bv, Vtb, BN_, HKV_*D_,  E_);

  // causal GQA flash attention
  attn_kernel<<<dim3(8, B_*HQ_), dim3(256), 0, stream>>>(Qb, Kb, Vtb, Ob);

  // output projection (fp32 out)
  gemm_bt<1><<<dim3(32*16), dim3(256), 0, stream>>>(Ob, Wob, bo, out, BN_, E_, E_);
}

// Round 4
// 309.115 us; speedup vs baseline: 2.1782x; 1.1600x over previous
//
#include <hip/hip_runtime.h>
#include <hip/hip_bf16.h>

// FlashMultiHeadAttention: x -> QKV proj -> causal GQA flash attn -> out proj
// B=2 N=2048 E=2048 HQ=32 HKV=8 D=64 G=4. All compute in bf16 MFMA, fp32 accum.

#define B_   2
#define N_   2048
#define E_   2048
#define HQ_  32
#define HKV_ 8
#define D_   64
#define G_   4
#define BN_  (B_*N_)   // 4096 total rows

typedef __attribute__((ext_vector_type(8))) short bf16x8;
typedef __attribute__((ext_vector_type(4))) float f32x4;

#define MFMA16(a,b,c) __builtin_amdgcn_mfma_f32_16x16x32_bf16(a,b,c,0,0,0)

__device__ inline unsigned short f2bf(float f) {
  unsigned u = __builtin_bit_cast(unsigned, f);
  u += 0x7FFFu + ((u >> 16) & 1u);   // RNE
  return (unsigned short)(u >> 16);
}

__device__ inline void gload_lds16(const void* g, void* l) {
  __builtin_amdgcn_global_load_lds(
      (const __attribute__((address_space(1))) void*)g,
      (__attribute__((address_space(3))) void*)l, 16, 0, 0);
}

// ---------------- fused cast fp32 -> bf16 for x,Wq,Wk,Wv,Wo ----------------
// Destinations are contiguous in ws in the same order, so dst offset == global idx.
__global__ void cast_all(const float* __restrict__ x,  const float* __restrict__ wq,
                         const float* __restrict__ wk, const float* __restrict__ wv,
                         const float* __restrict__ wo, unsigned short* __restrict__ dst) {
  const int c0 = 2097152;            // x      (8388608 elems /4)
  const int c1 = c0 + 1048576;       // Wq
  const int c2 = c1 + 262144;        // Wk
  const int c3 = c2 + 262144;        // Wv
  const int c4 = c3 + 1048576;       // Wo
  int i = blockIdx.x * blockDim.x + threadIdx.x;
  const int stride = gridDim.x * blockDim.x;
  for (; i < c4; i += stride) {
    const float* src; int off;
    if      (i < c0) { src = x;  off = i; }
    else if (i < c1) { src = wq; off = i - c0; }
    else if (i < c2) { src = wk; off = i - c1; }
    else if (i < c3) { src = wv; off = i - c2; }
    else             { src = wo; off = i - c3; }
    float4 f = reinterpret_cast<const float4*>(src)[off];
    ushort4 u;
    u.x = f2bf(f.x); u.y = f2bf(f.y); u.z = f2bf(f.z); u.w = f2bf(f.w);
    reinterpret_cast<ushort4*>(dst)[i] = u;
  }
}

// ---------------- fused QKV projection GEMM ----------------
// A[4096][2048] bf16. Virtual Nout = 2048(Q) + 512(K) + 512(V->transposed).
// 128x128 tile, BK=32, 4 waves x 64x64. m97-style global_load_lds staging.
__global__ __launch_bounds__(256) void gemm_qkv(
    const unsigned short* __restrict__ A,
    const unsigned short* __restrict__ Wq, const unsigned short* __restrict__ Wk,
    const unsigned short* __restrict__ Wv,
    const float* __restrict__ bq, const float* __restrict__ bk, const float* __restrict__ bv,
    unsigned short* __restrict__ Qo, unsigned short* __restrict__ Ko,
    unsigned short* __restrict__ Vto)
{
  __shared__ unsigned short As[128*32];
  __shared__ unsigned short Bs[128*32];
  const int tid  = threadIdx.x;
  const int w    = tid >> 6;
  const int lane = tid & 63;
  const int bm   = blockIdx.x / 24;
  const int bn   = blockIdx.x - bm * 24;
  const int m0   = bm << 7, n0 = bn << 7;
  const int K    = E_;

  const unsigned short* W; const float* bias; int wn0, seg;
  if      (n0 < 2048) { W = Wq; bias = bq; wn0 = n0;        seg = 0; }
  else if (n0 < 2560) { W = Wk; bias = bk; wn0 = n0 - 2048; seg = 1; }
  else                { W = Wv; bias = bv; wn0 = n0 - 2560; seg = 2; }

  const int wr   = (w >> 1) << 6;
  const int wc   = (w & 1) << 6;
  const int cl   = lane & 15;
  const int kgrp = lane >> 4;
  const int rl   = kgrp << 2;

  const int srow = w << 5;
  const int r0   = lane >> 2;
  const int c0e  = (lane & 3) << 3;
  const unsigned short* ga0 = A + (size_t)(m0 + srow + r0) * K + c0e;
  const unsigned short* ga1 = A + (size_t)(m0 + srow + 16 + r0) * K + c0e;
  const unsigned short* gb0 = W + (size_t)(wn0 + srow + r0) * K + c0e;
  const unsigned short* gb1 = W + (size_t)(wn0 + srow + 16 + r0) * K + c0e;
  unsigned short* la0 = As + (w << 10);
  unsigned short* la1 = As + (w << 10) + 512;
  unsigned short* lb0 = Bs + (w << 10);
  unsigned short* lb1 = Bs + (w << 10) + 512;

  f32x4 acc[4][4] = {};

  for (int kt = 0; kt < (K >> 5); ++kt) {
    const int ko = kt << 5;
    gload_lds16(ga0 + ko, la0);
    gload_lds16(ga1 + ko, la1);
    gload_lds16(gb0 + ko, lb0);
    gload_lds16(gb1 + ko, lb1);
    __syncthreads();
    bf16x8 af[4], bfr[4];
    #pragma unroll
    for (int i = 0; i < 4; ++i)
      af[i] = *reinterpret_cast<const bf16x8*>(&As[(wr + i*16 + cl)*32 + (kgrp << 3)]);
    #pragma unroll
    for (int j = 0; j < 4; ++j)
      bfr[j] = *reinterpret_cast<const bf16x8*>(&Bs[(wc + j*16 + cl)*32 + (kgrp << 3)]);
    #pragma unroll
    for (int i = 0; i < 4; ++i)
      #pragma unroll
      for (int j = 0; j < 4; ++j)
        acc[i][j] = MFMA16(af[i], bfr[j], acc[i][j]);
    __syncthreads();
  }

  if (seg == 0) {
    #pragma unroll
    for (int j = 0; j < 4; ++j) {
      const int col = wn0 + wc + j*16 + cl;
      const float bj = bias[col];
      #pragma unroll
      for (int i = 0; i < 4; ++i) {
        const int row = m0 + wr + i*16 + rl;
        #pragma unroll
        for (int r = 0; r < 4; ++r)
          Qo[(size_t)(row + r) * 2048 + col] = f2bf(acc[i][j][r] + bj);
      }
    }
  } else if (seg == 1) {
    #pragma unroll
    for (int j = 0; j < 4; ++j) {
      const int col = wn0 + wc + j*16 + cl;
      const float bj = bias[col];
      #pragma unroll
      for (int i = 0; i < 4; ++i) {
        const int row = m0 + wr + i*16 + rl;
        #pragma unroll
        for (int r = 0; r < 4; ++r)
          Ko[(size_t)(row + r) * 512 + col] = f2bf(acc[i][j][r] + bj);
      }
    }
  } else {
    // V transposed: Vt[col][row], ld = 4096
    #pragma unroll
    for (int j = 0; j < 4; ++j) {
      const int col = wn0 + wc + j*16 + cl;
      const float bj = bias[col];
      #pragma unroll
      for (int i = 0; i < 4; ++i) {
        const int rowb = m0 + wr + i*16 + rl;
        ushort4 u;
        u.x = f2bf(acc[i][j][0] + bj);
        u.y = f2bf(acc[i][j][1] + bj);
        u.z = f2bf(acc[i][j][2] + bj);
        u.w = f2bf(acc[i][j][3] + bj);
        *reinterpret_cast<ushort4*>(&Vto[(size_t)col * 4096 + rowb]) = u;
      }
    }
  }
}

// ---------------- out-proj GEMM (fp32 out) ----------------
__global__ __launch_bounds__(256) void gemm_out(
    const unsigned short* __restrict__ A, const unsigned short* __restrict__ W,
    const float* __restrict__ bias, float* __restrict__ C)
{
  __shared__ unsigned short As[128*32];
  __shared__ unsigned short Bs[128*32];
  const int tid  = threadIdx.x;
  const int w    = tid >> 6;
  const int lane = tid & 63;
  const int bm   = blockIdx.x >> 4;
  const int bn   = blockIdx.x & 15;
  const int m0   = bm << 7, n0 = bn << 7;
  const int K    = E_;
  const int wr   = (w >> 1) << 6;
  const int wc   = (w & 1) << 6;
  const int cl   = lane & 15;
  const int kgrp = lane >> 4;
  const int rl   = kgrp << 2;

  const int srow = w << 5;
  const int r0   = lane >> 2;
  const int c0e  = (lane & 3) << 3;
  const unsigned short* ga0 = A + (size_t)(m0 + srow + r0) * K + c0e;
  const unsigned short* ga1 = A + (size_t)(m0 + srow + 16 + r0) * K + c0e;
  const unsigned short* gb0 = W + (size_t)(n0 + srow + r0) * K + c0e;
  const unsigned short* gb1 = W + (size_t)(n0 + srow + 16 + r0) * K + c0e;
  unsigned short* la0 = As + (w << 10);
  unsigned short* la1 = As + (w << 10) + 512;
  unsigned short* lb0 = Bs + (w << 10);
  unsigned short* lb1 = Bs + (w << 10) + 512;

  f32x4 acc[4][4] = {};

  for (int kt = 0; kt < (K >> 5); ++kt) {
    const int ko = kt << 5;
    gload_lds16(ga0 + ko, la0);
    gload_lds16(ga1 + ko, la1);
    gload_lds16(gb0 + ko, lb0);
    gload_lds16(gb1 + ko, lb1);
    __syncthreads();
    bf16x8 af[4], bfr[4];
    #pragma unroll
    for (int i = 0; i < 4; ++i)
      af[i] = *reinterpret_cast<const bf16x8*>(&As[(wr + i*16 + cl)*32 + (kgrp << 3)]);
    #pragma unroll
    for (int j = 0; j < 4; ++j)
      bfr[j] = *reinterpret_cast<const bf16x8*>(&Bs[(wc + j*16 + cl)*32 + (kgrp << 3)]);
    #pragma unroll
    for (int i = 0; i < 4; ++i)
      #pragma unroll
      for (int j = 0; j < 4; ++j)
        acc[i][j] = MFMA16(af[i], bfr[j], acc[i][j]);
    __syncthreads();
  }

  #pragma unroll
  for (int j = 0; j < 4; ++j) {
    const int col = n0 + wc + j*16 + cl;
    const float bj = bias[col];
    #pragma unroll
    for (int i = 0; i < 4; ++i) {
      const int row = m0 + wr + i*16 + rl;
      #pragma unroll
      for (int r = 0; r < 4; ++r)
        C[(size_t)(row + r) * E_ + col] = acc[i][j][r] + bj;
    }
  }
}

// ---------------- causal GQA flash attention (v4) ----------------
// grid (16, 64), 4 waves/block. slot = bx*4+w (0..63): pairId = slot>>1 (0..31),
// half = slot&1. Wave handles kv-half of strip pair (pairId, 63-pairId); the two
// halves merge via LDS once per strip. Per strip: 32 q rows (2 i-blocks of 16),
// KVBLK=32. Softmax: EXACT per-tile max via 4-step shuffle reduce (round-2
// known-good); row-sum l via MFMA with all-ones B fragment (no sum shuffles).
__global__ __launch_bounds__(256, 3) void attn_kernel(
    const unsigned short* __restrict__ Q, const unsigned short* __restrict__ K,
    const unsigned short* __restrict__ Vt, unsigned short* __restrict__ O)
{
  __shared__ __align__(16) unsigned short Ps[4*1024];   // 8KB: per-wave P buffer
  __shared__ __align__(16) float Pm[2][48*64];          // 24KB: per-pair merge buffer
  const int tid  = threadIdx.x;
  const int w    = tid >> 6;
  const int lane = tid & 63;
  const int head = blockIdx.y;
  const int b    = head >> 5;
  const int hq   = head & 31;
  const int h    = hq >> 2;
  const int slot = blockIdx.x * 4 + w;
  const int pairId = slot >> 1;
  const int half = slot & 1;
  const int cl   = lane & 15;
  const int kgrp = lane >> 4;
  const int rl   = kgrp << 2;

  const float K2  = 0.125f * 1.44269504088896340736f;  // SCALE * log2(e)

  unsigned short* pw = Ps + w*1024;
  float* mb = Pm[w >> 1];

  bf16x8 ones8;
  #pragma unroll
  for (int j = 0; j < 8; ++j) ones8[j] = (short)0x3F80;   // bf16 1.0

  // uniform bases + per-lane static byte offsets (32-bit voffsets)
  const char* Kp = (const char*)(K + (size_t)(b*N_)*512 + h*64);
  const char* Vp = (const char*)(Vt + (size_t)(h*64)*BN_ + b*N_);
  const unsigned lkb = (unsigned)cl*1024u + (unsigned)kgrp*16u;       // K lane offset
  const unsigned lvb = (unsigned)cl*8192u + (unsigned)kgrp*16u;       // V lane offset

  for (int sp = 0; sp < 2; ++sp) {
    const int sidx = sp ? (63 - pairId) : pairId;
    const int q0   = sidx << 5;
    const int nt   = sidx + 1;
    const int th0  = (nt + 1) >> 1;
    const int t_lo = half ? th0 : 0;
    const int t_hi = half ? nt  : th0;

    bf16x8 qf[2][2];
    #pragma unroll
    for (int i = 0; i < 2; ++i) {
      const size_t qoff = (size_t)(b*N_ + q0 + i*16 + cl) * E_ + hq*64 + (kgrp << 3);
      qf[i][0] = *reinterpret_cast<const bf16x8*>(Q + qoff);
      qf[i][1] = *reinterpret_cast<const bf16x8*>(Q + qoff + 32);
    }

    f32x4 o[2][4] = {};
    f32x4 l4[2] = {};
    float m[2][4];
    #pragma unroll
    for (int i = 0; i < 2; ++i)
      #pragma unroll
      for (int r = 0; r < 4; ++r) m[i][r] = -1e30f;

    unsigned kvo = (unsigned)t_lo * 32768u;   // K: 32 rows x 1024B per tile
    unsigned vvo = (unsigned)t_lo * 64u;      // V: 32 cols x 2B per tile

    for (int t = t_lo; t < t_hi; ++t) {
      // ---- K / V loads (L2-resident) ----
      bf16x8 kf0a = *reinterpret_cast<const bf16x8*>(Kp + (kvo + lkb));
      bf16x8 kf0b = *reinterpret_cast<const bf16x8*>(Kp + (kvo + lkb + 64u));
      bf16x8 kf1a = *reinterpret_cast<const bf16x8*>(Kp + (kvo + lkb + 16384u));
      bf16x8 kf1b = *reinterpret_cast<const bf16x8*>(Kp + (kvo + lkb + 16448u));
      bf16x8 vf[4];
      #pragma unroll
      for (int db = 0; db < 4; ++db)
        vf[db] = *reinterpret_cast<const bf16x8*>(Vp + (vvo + lvb + (unsigned)db*131072u));

      // ---- S = Q K^T ----
      f32x4 s[2][2];
      #pragma unroll
      for (int i = 0; i < 2; ++i) {
        f32x4 z0 = {}, z1 = {};
        z0 = MFMA16(qf[i][0], kf0a, z0);
        z0 = MFMA16(qf[i][1], kf0b, z0);
        z1 = MFMA16(qf[i][0], kf1a, z1);
        z1 = MFMA16(qf[i][1], kf1b, z1);
        s[i][0] = z0; s[i][1] = z1;
      }

      // ---- causal mask (diagonal tile only) ----
      if (t == sidx) {
        const int kv0 = t << 5;
        #pragma unroll
        for (int i = 0; i < 2; ++i)
          #pragma unroll
          for (int c = 0; c < 2; ++c)
            #pragma unroll
            for (int r = 0; r < 4; ++r)
              if (kv0 + c*16 + cl > q0 + i*16 + rl + r) s[i][c][r] = -1e30f;
      }

      // ---- exact online softmax: per-tile row max via 4-step shuffle ----
      float tm[2][4];
      #pragma unroll
      for (int i = 0; i < 2; ++i)
        #pragma unroll
        for (int r = 0; r < 4; ++r) tm[i][r] = fmaxf(s[i][0][r], s[i][1][r]);
      #pragma unroll
      for (int off = 1; off < 16; off <<= 1)
        #pragma unroll
        for (int i = 0; i < 2; ++i)
          #pragma unroll
          for (int r = 0; r < 4; ++r)
            tm[i][r] = fmaxf(tm[i][r], __shfl_xor(tm[i][r], off, 64));
      float arg[2][2][4];
      #pragma unroll
      for (int i = 0; i < 2; ++i)
        #pragma unroll
        for (int r = 0; r < 4; ++r) {
          const float mn = fmaxf(m[i][r], tm[i][r]);
          const float al = __builtin_amdgcn_exp2f(K2 * (m[i][r] - mn));
          m[i][r] = mn;
          l4[i][r] *= al;
          #pragma unroll
          for (int db = 0; db < 4; ++db) o[i][db][r] *= al;
          #pragma unroll
          for (int c = 0; c < 2; ++c)
            arg[i][c][r] = K2 * (s[i][c][r] - mn);
        }

      // ---- P = exp2(arg) -> swizzled LDS ----
      #pragma unroll
      for (int i = 0; i < 2; ++i)
        #pragma unroll
        for (int c = 0; c < 2; ++c)
          #pragma unroll
          for (int r = 0; r < 4; ++r)
            pw[(i*16 + rl + r)*32 + ((((c << 1) + (cl >> 3)) ^ kgrp) << 3) + (cl & 7)]
                = f2bf(__builtin_amdgcn_exp2f(arg[i][c][r]));

      // ---- O += P V ; l += P . 1 ----
      #pragma unroll
      for (int i = 0; i < 2; ++i) {
        const bf16x8 pa = *reinterpret_cast<const bf16x8*>(
            &pw[(i*16 + cl)*32 + ((kgrp ^ (cl >> 2)) << 3)]);
        l4[i] = MFMA16(pa, ones8, l4[i]);
        #pragma unroll
        for (int db = 0; db < 4; ++db)
          o[i][db] = MFMA16(pa, vf[db], o[i][db]);
      }
      kvo += 32768u; vvo += 64u;
    }

    // ---- cross-wave merge of kv-halves ----
    if (half) {
      #pragma unroll
      for (int i = 0; i < 2; ++i) {
        #pragma unroll
        for (int db = 0; db < 4; ++db)
          #pragma unroll
          for (int r = 0; r < 4; ++r)
            mb[(i*16 + db*4 + r)*64 + lane] = o[i][db][r];
        #pragma unroll
        for (int r = 0; r < 4; ++r) {
          mb[(32 + i*4 + r)*64 + lane] = m[i][r];
          mb[(40 + i*4 + r)*64 + lane] = l4[i][r];
        }
      }
    }
    __syncthreads();
    if (!half) {
      #pragma unroll
      for (int i = 0; i < 2; ++i)
        #pragma unroll
        for (int r = 0; r < 4; ++r) {
          const float m1 = mb[(32 + i*4 + r)*64 + lane];
          const float l1 = mb[(40 + i*4 + r)*64 + lane];
          const float M  = fmaxf(m[i][r], m1);
          const float a0 = __builtin_amdgcn_exp2f(K2 * (m[i][r] - M));
          const float a1 = __builtin_amdgcn_exp2f(K2 * (m1 - M));
          const float li = 1.0f / (l4[i][r]*a0 + l1*a1);
          const size_t orow = (size_t)(b*N_ + q0 + i*16 + rl + r) * E_ + hq*64;
          #pragma unroll
          for (int db = 0; db < 4; ++db) {
            const float ov = o[i][db][r]*a0 + mb[(i*16 + db*4 + r)*64 + lane]*a1;
            O[orow + db*16 + cl] = f2bf(ov * li);
          }
        }
    }
    __syncthreads();
  }
}

extern "C" void kernel_launch(void* const* d_in, const int* in_sizes, int n_in,
                              void* d_out, int out_size, void* d_ws, size_t ws_size,
                              hipStream_t stream) {
  const float* x  = (const float*)d_in[0];
  const float* Wq = (const float*)d_in[1];
  const float* bq = (const float*)d_in[2];
  const float* Wk = (const float*)d_in[3];
  const float* bk = (const float*)d_in[4];
  const float* Wv = (const float*)d_in[5];
  const float* bv = (const float*)d_in[6];
  const float* Wo = (const float*)d_in[7];
  const float* bo = (const float*)d_in[8];
  float* out = (float*)d_out;

  // workspace carve (bf16 elements); cast destinations contiguous in input order
  unsigned short* ws  = (unsigned short*)d_ws;
  unsigned short* xb  = ws;              // 4096x2048
  unsigned short* Wqb = xb  + 8388608;   // 2048x2048
  unsigned short* Wkb = Wqb + 4194304;   // 512x2048
  unsigned short* Wvb = Wkb + 1048576;   // 512x2048
  unsigned short* Wob = Wvb + 1048576;   // 2048x2048
  unsigned short* Qb  = Wob + 4194304;   // 4096x2048
  unsigned short* Kb  = Qb  + 8388608;   // 4096x512
  unsigned short* Vtb = Kb  + 2097152;   // 512x4096 (V transposed)
  unsigned short* Ob  = Vtb + 2097152;   // 4096x2048

  cast_all<<<dim3(2048), dim3(256), 0, stream>>>(x, Wq, Wk, Wv, Wo, xb);

  gemm_qkv<<<dim3(32*24), dim3(256), 0, stream>>>(xb, Wqb, Wkb, Wvb,
                                                  bq, bk, bv, Qb, Kb, Vtb);

  attn_kernel<<<dim3(16, B_*HQ_), dim3(256), 0, stream>>>(Qb, Kb, Vtb, Ob);

  gemm_out<<<dim3(32*16), dim3(256), 0, stream>>>(Ob, Wob, bo, out);
}

// Round 5
// 281.216 us; speedup vs baseline: 2.3943x; 1.0992x over previous
//
#include <hip/hip_runtime.h>
#include <hip/hip_bf16.h>

// FlashMultiHeadAttention: x -> QKV proj -> causal GQA flash attn -> out proj
// B=2 N=2048 E=2048 HQ=32 HKV=8 D=64 G=4. All compute in bf16 MFMA, fp32 accum.

#define B_   2
#define N_   2048
#define E_   2048
#define HQ_  32
#define HKV_ 8
#define D_   64
#define G_   4
#define BN_  (B_*N_)   // 4096 total rows

typedef __attribute__((ext_vector_type(8))) short bf16x8;
typedef __attribute__((ext_vector_type(4))) float f32x4;

#define MFMA16(a,b,c) __builtin_amdgcn_mfma_f32_16x16x32_bf16(a,b,c,0,0,0)

__device__ inline unsigned short f2bf(float f) {
  unsigned u = __builtin_bit_cast(unsigned, f);
  u += 0x7FFFu + ((u >> 16) & 1u);   // RNE
  return (unsigned short)(u >> 16);
}

__device__ inline void gload_lds16(const void* g, void* l) {
  __builtin_amdgcn_global_load_lds(
      (const __attribute__((address_space(1))) void*)g,
      (__attribute__((address_space(3))) void*)l, 16, 0, 0);
}

// ---------------- fused cast fp32 -> bf16 for x,Wq,Wk,Wv,Wo ----------------
__global__ void cast_all(const float* __restrict__ x,  const float* __restrict__ wq,
                         const float* __restrict__ wk, const float* __restrict__ wv,
                         const float* __restrict__ wo, unsigned short* __restrict__ dst) {
  const int c0 = 2097152;            // x      (8388608 elems /4)
  const int c1 = c0 + 1048576;       // Wq
  const int c2 = c1 + 262144;        // Wk
  const int c3 = c2 + 262144;        // Wv
  const int c4 = c3 + 1048576;       // Wo
  int i = blockIdx.x * blockDim.x + threadIdx.x;
  const int stride = gridDim.x * blockDim.x;
  for (; i < c4; i += stride) {
    const float* src; int off;
    if      (i < c0) { src = x;  off = i; }
    else if (i < c1) { src = wq; off = i - c0; }
    else if (i < c2) { src = wk; off = i - c1; }
    else if (i < c3) { src = wv; off = i - c2; }
    else             { src = wo; off = i - c3; }
    float4 f = reinterpret_cast<const float4*>(src)[off];
    ushort4 u;
    u.x = f2bf(f.x); u.y = f2bf(f.y); u.z = f2bf(f.z); u.w = f2bf(f.w);
    reinterpret_cast<ushort4*>(dst)[i] = u;
  }
}

// ---------------- fused QKV projection GEMM ----------------
__global__ __launch_bounds__(256) void gemm_qkv(
    const unsigned short* __restrict__ A,
    const unsigned short* __restrict__ Wq, const unsigned short* __restrict__ Wk,
    const unsigned short* __restrict__ Wv,
    const float* __restrict__ bq, const float* __restrict__ bk, const float* __restrict__ bv,
    unsigned short* __restrict__ Qo, unsigned short* __restrict__ Ko,
    unsigned short* __restrict__ Vto)
{
  __shared__ unsigned short As[128*32];
  __shared__ unsigned short Bs[128*32];
  const int tid  = threadIdx.x;
  const int w    = tid >> 6;
  const int lane = tid & 63;
  const int bm   = blockIdx.x / 24;
  const int bn   = blockIdx.x - bm * 24;
  const int m0   = bm << 7, n0 = bn << 7;
  const int K    = E_;

  const unsigned short* W; const float* bias; int wn0, seg;
  if      (n0 < 2048) { W = Wq; bias = bq; wn0 = n0;        seg = 0; }
  else if (n0 < 2560) { W = Wk; bias = bk; wn0 = n0 - 2048; seg = 1; }
  else                { W = Wv; bias = bv; wn0 = n0 - 2560; seg = 2; }

  const int wr   = (w >> 1) << 6;
  const int wc   = (w & 1) << 6;
  const int cl   = lane & 15;
  const int kgrp = lane >> 4;
  const int rl   = kgrp << 2;

  const int srow = w << 5;
  const int r0   = lane >> 2;
  const int c0e  = (lane & 3) << 3;
  const unsigned short* ga0 = A + (size_t)(m0 + srow + r0) * K + c0e;
  const unsigned short* ga1 = A + (size_t)(m0 + srow + 16 + r0) * K + c0e;
  const unsigned short* gb0 = W + (size_t)(wn0 + srow + r0) * K + c0e;
  const unsigned short* gb1 = W + (size_t)(wn0 + srow + 16 + r0) * K + c0e;
  unsigned short* la0 = As + (w << 10);
  unsigned short* la1 = As + (w << 10) + 512;
  unsigned short* lb0 = Bs + (w << 10);
  unsigned short* lb1 = Bs + (w << 10) + 512;

  f32x4 acc[4][4] = {};

  for (int kt = 0; kt < (K >> 5); ++kt) {
    const int ko = kt << 5;
    gload_lds16(ga0 + ko, la0);
    gload_lds16(ga1 + ko, la1);
    gload_lds16(gb0 + ko, lb0);
    gload_lds16(gb1 + ko, lb1);
    __syncthreads();
    bf16x8 af[4], bfr[4];
    #pragma unroll
    for (int i = 0; i < 4; ++i)
      af[i] = *reinterpret_cast<const bf16x8*>(&As[(wr + i*16 + cl)*32 + (kgrp << 3)]);
    #pragma unroll
    for (int j = 0; j < 4; ++j)
      bfr[j] = *reinterpret_cast<const bf16x8*>(&Bs[(wc + j*16 + cl)*32 + (kgrp << 3)]);
    #pragma unroll
    for (int i = 0; i < 4; ++i)
      #pragma unroll
      for (int j = 0; j < 4; ++j)
        acc[i][j] = MFMA16(af[i], bfr[j], acc[i][j]);
    __syncthreads();
  }

  if (seg == 0) {
    #pragma unroll
    for (int j = 0; j < 4; ++j) {
      const int col = wn0 + wc + j*16 + cl;
      const float bj = bias[col];
      #pragma unroll
      for (int i = 0; i < 4; ++i) {
        const int row = m0 + wr + i*16 + rl;
        #pragma unroll
        for (int r = 0; r < 4; ++r)
          Qo[(size_t)(row + r) * 2048 + col] = f2bf(acc[i][j][r] + bj);
      }
    }
  } else if (seg == 1) {
    #pragma unroll
    for (int j = 0; j < 4; ++j) {
      const int col = wn0 + wc + j*16 + cl;
      const float bj = bias[col];
      #pragma unroll
      for (int i = 0; i < 4; ++i) {
        const int row = m0 + wr + i*16 + rl;
        #pragma unroll
        for (int r = 0; r < 4; ++r)
          Ko[(size_t)(row + r) * 512 + col] = f2bf(acc[i][j][r] + bj);
      }
    }
  } else {
    // V transposed: Vt[col][row], ld = 4096
    #pragma unroll
    for (int j = 0; j < 4; ++j) {
      const int col = wn0 + wc + j*16 + cl;
      const float bj = bias[col];
      #pragma unroll
      for (int i = 0; i < 4; ++i) {
        const int rowb = m0 + wr + i*16 + rl;
        ushort4 u;
        u.x = f2bf(acc[i][j][0] + bj);
        u.y = f2bf(acc[i][j][1] + bj);
        u.z = f2bf(acc[i][j][2] + bj);
        u.w = f2bf(acc[i][j][3] + bj);
        *reinterpret_cast<ushort4*>(&Vto[(size_t)col * 4096 + rowb]) = u;
      }
    }
  }
}

// ---------------- out-proj GEMM (fp32 out) ----------------
__global__ __launch_bounds__(256) void gemm_out(
    const unsigned short* __restrict__ A, const unsigned short* __restrict__ W,
    const float* __restrict__ bias, float* __restrict__ C)
{
  __shared__ unsigned short As[128*32];
  __shared__ unsigned short Bs[128*32];
  const int tid  = threadIdx.x;
  const int w    = tid >> 6;
  const int lane = tid & 63;
  const int bm   = blockIdx.x >> 4;
  const int bn   = blockIdx.x & 15;
  const int m0   = bm << 7, n0 = bn << 7;
  const int K    = E_;
  const int wr   = (w >> 1) << 6;
  const int wc   = (w & 1) << 6;
  const int cl   = lane & 15;
  const int kgrp = lane >> 4;
  const int rl   = kgrp << 2;

  const int srow = w << 5;
  const int r0   = lane >> 2;
  const int c0e  = (lane & 3) << 3;
  const unsigned short* ga0 = A + (size_t)(m0 + srow + r0) * K + c0e;
  const unsigned short* ga1 = A + (size_t)(m0 + srow + 16 + r0) * K + c0e;
  const unsigned short* gb0 = W + (size_t)(n0 + srow + r0) * K + c0e;
  const unsigned short* gb1 = W + (size_t)(n0 + srow + 16 + r0) * K + c0e;
  unsigned short* la0 = As + (w << 10);
  unsigned short* la1 = As + (w << 10) + 512;
  unsigned short* lb0 = Bs + (w << 10);
  unsigned short* lb1 = Bs + (w << 10) + 512;

  f32x4 acc[4][4] = {};

  for (int kt = 0; kt < (K >> 5); ++kt) {
    const int ko = kt << 5;
    gload_lds16(ga0 + ko, la0);
    gload_lds16(ga1 + ko, la1);
    gload_lds16(gb0 + ko, lb0);
    gload_lds16(gb1 + ko, lb1);
    __syncthreads();
    bf16x8 af[4], bfr[4];
    #pragma unroll
    for (int i = 0; i < 4; ++i)
      af[i] = *reinterpret_cast<const bf16x8*>(&As[(wr + i*16 + cl)*32 + (kgrp << 3)]);
    #pragma unroll
    for (int j = 0; j < 4; ++j)
      bfr[j] = *reinterpret_cast<const bf16x8*>(&Bs[(wc + j*16 + cl)*32 + (kgrp << 3)]);
    #pragma unroll
    for (int i = 0; i < 4; ++i)
      #pragma unroll
      for (int j = 0; j < 4; ++j)
        acc[i][j] = MFMA16(af[i], bfr[j], acc[i][j]);
    __syncthreads();
  }

  #pragma unroll
  for (int j = 0; j < 4; ++j) {
    const int col = n0 + wc + j*16 + cl;
    const float bj = bias[col];
    #pragma unroll
    for (int i = 0; i < 4; ++i) {
      const int row = m0 + wr + i*16 + rl;
      #pragma unroll
      for (int r = 0; r < 4; ++r)
        C[(size_t)(row + r) * E_ + col] = acc[i][j][r] + bj;
    }
  }
}

// ---------------- causal GQA flash attention (v5: swapped operands) ----------------
// grid (8, 64), 4 waves/block, waves fully independent. Wave j = bx*4+w (0..31)
// handles balanced strip pair (j, 63-j); strip = 32 q rows (2 i-blocks of 16).
// KVBLK=64 (4 c-blocks of 16). Swapped MFMA: S^T = mfma(K, Q) -> lane owns ONE
// q (=lane&15) per i-block; softmax max = 15 lane-local fmax + 2 shuffles;
// state m/alpha scalar per lane. O^T = mfma(V^T, P): V^T frags are the natural
// Vt loads; epilogue = contiguous ushort4 stores. l via ones-MFMA. K(t+1)
// prefetched after QK; V(t+1) after PV. P via XOR-swizzled LDS (b64 writes).
__global__ __launch_bounds__(256, 2) void attn_kernel(
    const unsigned short* __restrict__ Q, const unsigned short* __restrict__ K,
    const unsigned short* __restrict__ Vt, unsigned short* __restrict__ O)
{
  __shared__ __align__(16) unsigned short Ps[4][2048];   // per-wave 2 i-blocks x [16 q][64 kv]
  const int tid  = threadIdx.x;
  const int w    = tid >> 6;
  const int lane = tid & 63;
  const int head = blockIdx.y;
  const int b    = head >> 5;
  const int hq   = head & 31;
  const int h    = hq >> 2;
  const int j    = blockIdx.x * 4 + w;   // 0..31
  const int cl   = lane & 15;
  const int kgrp = lane >> 4;
  const int rl   = kgrp << 2;

  const float K2 = 0.125f * 1.44269504088896340736f;  // SCALE * log2(e)

  char* pws = (char*)&Ps[w][0];
  const unsigned swz = ((unsigned)(cl & 7)) << 4;

  bf16x8 ones8;
  #pragma unroll
  for (int q = 0; q < 8; ++q) ones8[q] = (short)0x3F80;   // bf16 1.0

  // global bases + per-lane byte offsets
  const char* Kp = (const char*)(K + (size_t)(b*N_)*512 + h*64);
  const char* Vp = (const char*)(Vt + (size_t)(h*64)*BN_ + b*N_);
  const unsigned lkb = (unsigned)cl*1024u + (unsigned)kgrp*16u;  // K: row cl, d kgrp*8
  const unsigned lvb = (unsigned)cl*8192u + (unsigned)kgrp*16u;  // Vt: row d, kv kgrp*8

  // LDS byte offsets (write b64: 4 consecutive kv; read b128: 8 consecutive kv)
  unsigned wb[2][4], rb[2][2];
  #pragma unroll
  for (int i = 0; i < 2; ++i) {
    #pragma unroll
    for (int c = 0; c < 4; ++c)
      wb[i][c] = (unsigned)i*2048u + (unsigned)cl*128u
               + (((unsigned)c*32u + (unsigned)kgrp*8u) ^ swz);
    #pragma unroll
    for (int ks = 0; ks < 2; ++ks)
      rb[i][ks] = (unsigned)i*2048u + (unsigned)cl*128u
                + (((unsigned)ks*64u + (unsigned)kgrp*16u) ^ swz);
  }

  for (int sp = 0; sp < 2; ++sp) {
    const int sidx = sp ? (63 - j) : j;
    const int q0   = sidx << 5;
    const int nt   = (sidx >> 1) + 1;   // kv tiles of 64

    // Q fragments (B-operand): lane cl = q row
    bf16x8 qf[2][2];
    #pragma unroll
    for (int i = 0; i < 2; ++i) {
      const size_t qoff = (size_t)(b*N_ + q0 + i*16 + cl) * E_ + hq*64 + (kgrp << 3);
      qf[i][0] = *reinterpret_cast<const bf16x8*>(Q + qoff);
      qf[i][1] = *reinterpret_cast<const bf16x8*>(Q + qoff + 32);
    }

    f32x4 o[2][4] = {};    // O^T: o[i][db][r] = O[q=cl][d=db*16+rl+r]
    f32x4 l4[2] = {};      // l (all 4 entries equal)
    float m[2] = {-1e30f, -1e30f};

    unsigned kvoK = 0, kvoV = 0;

    // prologue: K,V for tile 0
    bf16x8 kf[4][2], vf[4][2];
    #pragma unroll
    for (int c = 0; c < 4; ++c) {
      kf[c][0] = *reinterpret_cast<const bf16x8*>(Kp + (lkb + (unsigned)c*16384u));
      kf[c][1] = *reinterpret_cast<const bf16x8*>(Kp + (lkb + (unsigned)c*16384u + 64u));
    }
    #pragma unroll
    for (int db = 0; db < 4; ++db) {
      vf[db][0] = *reinterpret_cast<const bf16x8*>(Vp + (lvb + (unsigned)db*131072u));
      vf[db][1] = *reinterpret_cast<const bf16x8*>(Vp + (lvb + (unsigned)db*131072u + 64u));
    }

    for (int t = 0; t < nt; ++t) {
      // ---- S^T = K Q (row = kv, col = q) ----
      f32x4 s[2][4];
      #pragma unroll
      for (int i = 0; i < 2; ++i)
        #pragma unroll
        for (int c = 0; c < 4; ++c) {
          f32x4 z = {};
          z = MFMA16(kf[c][0], qf[i][0], z);
          z = MFMA16(kf[c][1], qf[i][1], z);
          s[i][c] = z;
        }

      // ---- prefetch K(t+1) (hidden under softmax+PV) ----
      const unsigned kvoKn = (t + 1 < nt) ? (kvoK + 65536u) : kvoK;
      bf16x8 kfn[4][2];
      #pragma unroll
      for (int c = 0; c < 4; ++c) {
        kfn[c][0] = *reinterpret_cast<const bf16x8*>(Kp + (kvoKn + lkb + (unsigned)c*16384u));
        kfn[c][1] = *reinterpret_cast<const bf16x8*>(Kp + (kvoKn + lkb + (unsigned)c*16384u + 64u));
      }

      // ---- causal mask (last tile only): kv > q -> -inf ----
      if (t == nt - 1) {
        const int kvb = t << 6;
        #pragma unroll
        for (int i = 0; i < 2; ++i) {
          const int qq = q0 + i*16 + cl;
          #pragma unroll
          for (int c = 0; c < 4; ++c)
            #pragma unroll
            for (int r = 0; r < 4; ++r)
              if (kvb + c*16 + rl + r > qq) s[i][c][r] = -1e30f;
        }
      }

      // ---- softmax: lane-local max tree + 2 shuffles; scalar state ----
      #pragma unroll
      for (int i = 0; i < 2; ++i) {
        float t0 = fmaxf(fmaxf(s[i][0][0], s[i][0][1]), fmaxf(s[i][0][2], s[i][0][3]));
        float t1 = fmaxf(fmaxf(s[i][1][0], s[i][1][1]), fmaxf(s[i][1][2], s[i][1][3]));
        float t2 = fmaxf(fmaxf(s[i][2][0], s[i][2][1]), fmaxf(s[i][2][2], s[i][2][3]));
        float t3 = fmaxf(fmaxf(s[i][3][0], s[i][3][1]), fmaxf(s[i][3][2], s[i][3][3]));
        float tm = fmaxf(fmaxf(t0, t1), fmaxf(t2, t3));
        tm = fmaxf(tm, __shfl_xor(tm, 16, 64));
        tm = fmaxf(tm, __shfl_xor(tm, 32, 64));
        const float mn = fmaxf(m[i], tm);
        const float al = __builtin_amdgcn_exp2f(K2 * (m[i] - mn));
        m[i] = mn;
        l4[i] *= al;
        #pragma unroll
        for (int db = 0; db < 4; ++db) o[i][db] *= al;
        // P = exp2(K2*(s - mn)) -> swizzled LDS (b64: 4 consecutive kv)
        #pragma unroll
        for (int c = 0; c < 4; ++c) {
          ushort4 u;
          u.x = f2bf(__builtin_amdgcn_exp2f(K2 * (s[i][c][0] - mn)));
          u.y = f2bf(__builtin_amdgcn_exp2f(K2 * (s[i][c][1] - mn)));
          u.z = f2bf(__builtin_amdgcn_exp2f(K2 * (s[i][c][2] - mn)));
          u.w = f2bf(__builtin_amdgcn_exp2f(K2 * (s[i][c][3] - mn)));
          *reinterpret_cast<ushort4*>(pws + wb[i][c]) = u;
        }
      }

      // ---- O^T += V^T P ; l += 1 . P ----
      #pragma unroll
      for (int i = 0; i < 2; ++i) {
        const bf16x8 pa0 = *reinterpret_cast<const bf16x8*>(pws + rb[i][0]);
        const bf16x8 pa1 = *reinterpret_cast<const bf16x8*>(pws + rb[i][1]);
        l4[i] = MFMA16(ones8, pa0, l4[i]);
        l4[i] = MFMA16(ones8, pa1, l4[i]);
        #pragma unroll
        for (int db = 0; db < 4; ++db) {
          o[i][db] = MFMA16(vf[db][0], pa0, o[i][db]);
          o[i][db] = MFMA16(vf[db][1], pa1, o[i][db]);
        }
      }

      // ---- prefetch V(t+1) (hidden under next QK+softmax) ----
      const unsigned kvoVn = (t + 1 < nt) ? (kvoV + 128u) : kvoV;
      #pragma unroll
      for (int db = 0; db < 4; ++db) {
        vf[db][0] = *reinterpret_cast<const bf16x8*>(Vp + (kvoVn + lvb + (unsigned)db*131072u));
        vf[db][1] = *reinterpret_cast<const bf16x8*>(Vp + (kvoVn + lvb + (unsigned)db*131072u + 64u));
      }
      #pragma unroll
      for (int c = 0; c < 4; ++c) { kf[c][0] = kfn[c][0]; kf[c][1] = kfn[c][1]; }
      kvoK = kvoKn; kvoV = kvoVn;
    }

    // ---- epilogue: O[q][hq*64 + d] = o/l (contiguous ushort4 per (i,db)) ----
    #pragma unroll
    for (int i = 0; i < 2; ++i) {
      const float inv = 1.0f / l4[i][0];
      const size_t orow = (size_t)(b*N_ + q0 + i*16 + cl) * E_ + hq*64 + rl;
      #pragma unroll
      for (int db = 0; db < 4; ++db) {
        ushort4 u;
        u.x = f2bf(o[i][db][0] * inv);
        u.y = f2bf(o[i][db][1] * inv);
        u.z = f2bf(o[i][db][2] * inv);
        u.w = f2bf(o[i][db][3] * inv);
        *reinterpret_cast<ushort4*>(&O[orow + db*16]) = u;
      }
    }
  }
}

extern "C" void kernel_launch(void* const* d_in, const int* in_sizes, int n_in,
                              void* d_out, int out_size, void* d_ws, size_t ws_size,
                              hipStream_t stream) {
  const float* x  = (const float*)d_in[0];
  const float* Wq = (const float*)d_in[1];
  const float* bq = (const float*)d_in[2];
  const float* Wk = (const float*)d_in[3];
  const float* bk = (const float*)d_in[4];
  const float* Wv = (const float*)d_in[5];
  const float* bv = (const float*)d_in[6];
  const float* Wo = (const float*)d_in[7];
  const float* bo = (const float*)d_in[8];
  float* out = (float*)d_out;

  // workspace carve (bf16 elements); cast destinations contiguous in input order
  unsigned short* ws  = (unsigned short*)d_ws;
  unsigned short* xb  = ws;              // 4096x2048
  unsigned short* Wqb = xb  + 8388608;   // 2048x2048
  unsigned short* Wkb = Wqb + 4194304;   // 512x2048
  unsigned short* Wvb = Wkb + 1048576;   // 512x2048
  unsigned short* Wob = Wvb + 1048576;   // 2048x2048
  unsigned short* Qb  = Wob + 4194304;   // 4096x2048
  unsigned short* Kb  = Qb  + 8388608;   // 4096x512
  unsigned short* Vtb = Kb  + 2097152;   // 512x4096 (V transposed)
  unsigned short* Ob  = Vtb + 2097152;   // 4096x2048

  cast_all<<<dim3(2048), dim3(256), 0, stream>>>(x, Wq, Wk, Wv, Wo, xb);

  gemm_qkv<<<dim3(32*24), dim3(256), 0, stream>>>(xb, Wqb, Wkb, Wvb,
                                                  bq, bk, bv, Qb, Kb, Vtb);

  attn_kernel<<<dim3(8, B_*HQ_), dim3(256), 0, stream>>>(Qb, Kb, Vtb, Ob);

  gemm_out<<<dim3(32*16), dim3(256), 0, stream>>>(Ob, Wob, bo, out);
}